// Round 6
// baseline (536.979 us; speedup 1.0000x reference)
//
#include <hip/hip_runtime.h>
#include <math.h>

#define TT 16384            // tokens
#define HD 4096             // hidden
#define NE 64               // experts
#define TM 32               // tokens per epilogue block
#define NBLK (TT / TM)      // 512 epilogue blocks
// ---- MFMA gemm geometry ----
#define TB5 32              // tokens per block
#define NB5 (TT / TB5)      // 512 blocks (2 per CU)
#define BK5 64              // h per staged tile
#define NKT5 (HD / BK5)     // 64 k-iterations
#define TAU 1e-5f           // near-tie fixup threshold (prob units)

typedef __attribute__((ext_vector_type(8))) short s8v;   // 8 x bf16
typedef __attribute__((ext_vector_type(4))) float f4v;   // MFMA acc

// ---- async global->LDS: dest wave-uniform base; HW adds lane*16 ----
__device__ __forceinline__ void async16(const void* src, void* dst) {
  __builtin_amdgcn_global_load_lds(
      (const __attribute__((address_space(1))) void*)src,
      (__attribute__((address_space(3))) void*)dst, 16, 0, 0);
}

#define FMA4(A, HV, WV)                                       \
  A = fmaf((HV).x, (WV).x, A); A = fmaf((HV).y, (WV).y, A);   \
  A = fmaf((HV).z, (WV).z, A); A = fmaf((HV).w, (WV).w, A);

// RNE float->bf16 (bit trick; inputs are normal randoms, no NaN)
__device__ __forceinline__ unsigned short f2bf(float f) {
  unsigned int u = __float_as_uint(f);
  return (unsigned short)((u + 0x7FFFu + ((u >> 16) & 1u)) >> 16);
}
__device__ __forceinline__ float bf2f(unsigned short h) {
  return __uint_as_float(((unsigned int)h) << 16);
}

__device__ __forceinline__ void split8(float4 a, float4 b, s8v& hi, s8v& lo) {
  float v[8] = {a.x, a.y, a.z, a.w, b.x, b.y, b.z, b.w};
#pragma unroll
  for (int i = 0; i < 8; ++i) {
    unsigned short h = f2bf(v[i]);
    unsigned short l = f2bf(v[i] - bf2f(h));
    hi[i] = (short)h; lo[i] = (short)l;
  }
}

// =====================================================================
// Kernel 0: W fp32 -> bf16 hi/lo planes in workspace.
// =====================================================================
__global__ void wconv(const float* __restrict__ W,
                      unsigned short* __restrict__ WH,
                      unsigned short* __restrict__ WL) {
  const int i = blockIdx.x * 256 + threadIdx.x;   // 65536 float4 groups
  const float4 v = *(const float4*)(W + (size_t)i * 4);
  float x[4] = {v.x, v.y, v.z, v.w};
#pragma unroll
  for (int j = 0; j < 4; ++j) {
    unsigned short h = f2bf(x[j]);
    WH[(size_t)i * 4 + j] = h;
    WL[(size_t)i * 4 + j] = f2bf(x[j] - bf2f(h));
  }
}

// =====================================================================
// Kernel 1: bf16x3 MFMA GEMM, logits -> part[t][e] fp32. (R5-validated,
// unchanged.)
// =====================================================================
__launch_bounds__(256, 2)
__global__ void gemm_mfma(const float* __restrict__ X,
                          const unsigned short* __restrict__ WH,
                          const unsigned short* __restrict__ WL,
                          float* __restrict__ part) {
  __shared__ __align__(16) float          sX[2][TB5 * BK5];  // 2 x 8 KB
  __shared__ __align__(16) unsigned short sH[2][NE * BK5];   // 2 x 8 KB
  __shared__ __align__(16) unsigned short sL[2][NE * BK5];   // 2 x 8 KB

  const int tid  = threadIdx.x;
  const int lane = tid & 63;
  const int w    = tid >> 6;
  const int t0   = blockIdx.x * TB5;

  const float* srcX[2];
#pragma unroll
  for (int ih = 0; ih < 2; ++ih) {
    const int row = w * 8 + ih * 4 + (lane >> 4);
    const int key = (ih * 4 + (lane >> 4)) & 7;          // row & 7
    const int c   = (lane & 15) ^ key;
    srcX[ih] = X + (size_t)(t0 + row) * HD + c * 4;
  }
  const unsigned short* srcH[2];
  const unsigned short* srcL[2];
#pragma unroll
  for (int ih = 0; ih < 2; ++ih) {
    const int e = w * 16 + ih * 8 + (lane >> 3);
    const int c = (lane & 7) ^ (lane >> 3);              // key = e & 7
    srcH[ih] = WH + (size_t)e * HD + c * 8;
    srcL[ih] = WL + (size_t)e * HD + c * 8;
  }

  auto stage = [&](int b, int kt) {
    const int o = kt * BK5;
#pragma unroll
    for (int ih = 0; ih < 2; ++ih)
      async16(srcX[ih] + o, &sX[b][(w * 8 + ih * 4) * BK5]);
#pragma unroll
    for (int ih = 0; ih < 2; ++ih)
      async16(srcH[ih] + o, &sH[b][(w * 16 + ih * 8) * BK5]);
#pragma unroll
    for (int ih = 0; ih < 2; ++ih)
      async16(srcL[ih] + o, &sL[b][(w * 16 + ih * 8) * BK5]);
  };

  const int fr    = lane & 15;
  const int fq    = lane >> 4;
  const int tloc  = (w >> 1) * 16 + fr;   // A-frag token row in block
  const int keyA  = fr & 7;               // tloc & 7
  const int ebase = (w & 1) * 32;

  f4v acc[2];
  acc[0] = (f4v)(0.0f); acc[1] = (f4v)(0.0f);

  int buf = 0;
  stage(0, 0);
  __syncthreads();
  for (int kt = 0; kt < NKT5; ++kt) {
    if (kt + 1 < NKT5) stage(buf ^ 1, kt + 1);
#pragma unroll
    for (int ks = 0; ks < 2; ++ks) {
      const int c0 = fq * 2 + ks * 8;
      const float4 xa = *(const float4*)(&sX[buf][tloc * BK5 + (((c0)     ^ keyA) << 2)]);
      const float4 xb = *(const float4*)(&sX[buf][tloc * BK5 + (((c0 + 1) ^ keyA) << 2)]);
      s8v ah, al;
      split8(xa, xb, ah, al);
#pragma unroll
      for (int nf = 0; nf < 2; ++nf) {
        const int eg = ebase + nf * 16 + fr;
        const int c  = (fq + ks * 4) ^ (eg & 7);
        const s8v bh = *(const s8v*)(&sH[buf][eg * BK5 + c * 8]);
        const s8v bl = *(const s8v*)(&sL[buf][eg * BK5 + c * 8]);
        acc[nf] = __builtin_amdgcn_mfma_f32_16x16x32_bf16(ah, bh, acc[nf], 0, 0, 0);
        acc[nf] = __builtin_amdgcn_mfma_f32_16x16x32_bf16(ah, bl, acc[nf], 0, 0, 0);
        acc[nf] = __builtin_amdgcn_mfma_f32_16x16x32_bf16(al, bh, acc[nf], 0, 0, 0);
      }
    }
    __syncthreads();
    buf ^= 1;
  }

#pragma unroll
  for (int nf = 0; nf < 2; ++nf) {
    const int e = ebase + nf * 16 + fr;
#pragma unroll
    for (int i = 0; i < 4; ++i) {
      const int t = t0 + (w >> 1) * 16 + fq * 4 + i;
      part[(size_t)t * NE + e] = acc[nf][i];
    }
  }
}

// =====================================================================
// Kernel 2: detect — flag tokens whose top-2/3 prob gaps are < TAU.
// One thread per token; fully unrolled (static indexing).
// =====================================================================
__global__ void detect(const float* __restrict__ part,
                       unsigned char* __restrict__ flag) {
  const int t = blockIdx.x * 256 + threadIdx.x;
  const float* pr = part + (size_t)t * NE;
  float l[NE];
  float m = -1e30f;
#pragma unroll
  for (int i = 0; i < 16; ++i) {
    const float4 v = *(const float4*)(pr + 4 * i);
    l[4 * i] = v.x; l[4 * i + 1] = v.y; l[4 * i + 2] = v.z; l[4 * i + 3] = v.w;
    m = fmaxf(m, fmaxf(fmaxf(v.x, v.y), fmaxf(v.z, v.w)));
  }
  float zs = 0.0f;
#pragma unroll
  for (int i = 0; i < NE; ++i) { l[i] = expf(l[i] - m); zs += l[i]; }
  // top-3 exp values (prob gap test in e-space: gap_p = gap_e / zs)
  float v1 = -1.0f, v2 = -1.0f, v3 = -1.0f;
#pragma unroll
  for (int i = 0; i < NE; ++i) {
    const float p = l[i];
    if (p > v1)      { v3 = v2; v2 = v1; v1 = p; }
    else if (p > v2) { v3 = v2; v2 = p; }
    else if (p > v3) { v3 = p; }
  }
  const float thr = TAU * zs;
  flag[t] = ((v1 - v2) < thr) || ((v2 - v3) < thr) ? 1 : 0;
}

// =====================================================================
// Kernel 3: fixup — for flagged tokens, block-cooperative exact fp32
// recompute of all 64 logits; overwrite part[t][*]. Thread = (expert e,
// H-quarter q); each sums 1024 elems serial-ascending; fixed-order
// 4-way combine. Deterministic.
// =====================================================================
__launch_bounds__(256, 4)
__global__ void fixup(const float* __restrict__ X,
                      const float* __restrict__ W,
                      const unsigned char* __restrict__ flag,
                      float* __restrict__ part) {
  __shared__ float red[NE][4];
  const int tid  = threadIdx.x;
  const int e    = tid >> 2;
  const int q    = tid & 3;
  const int base = blockIdx.x * 64;

  for (int j = 0; j < 64; ++j) {
    const int t = base + j;
    if (!flag[t]) continue;            // uniform branch (same t blockwide)
    const float* xr = X + (size_t)t * HD + q * 1024;
    const float* wr = W + (size_t)e * HD + q * 1024;
    float s = 0.0f;
    for (int h = 0; h < 1024; h += 4) {
      const float4 xv = *(const float4*)(xr + h);
      const float4 wv = *(const float4*)(wr + h);
      FMA4(s, xv, wv)
    }
    red[e][q] = s;
    __syncthreads();
    if (q == 0)
      part[(size_t)t * NE + e] = (red[e][0] + red[e][1]) + (red[e][2] + red[e][3]);
    __syncthreads();
  }
}

// =====================================================================
// Kernel 4: epilogue — validated R1 softmax/top-2/renorm/loss partials,
// reading (corrected) part directly. No recompute branch.
// =====================================================================
__global__ void router_epilogue(const float* __restrict__ part,
                                float* __restrict__ out,
                                float* __restrict__ pP,
                                float* __restrict__ pC,
                                float* __restrict__ pZ) {
  __shared__ float psW[4][NE];
  __shared__ float cf[NE];
  __shared__ float zb[4];

  const int tid  = threadIdx.x;
  const int blk  = blockIdx.x;
  const int tx   = tid & 15;   // expert group (4 experts each)
  const int ty   = tid >> 4;   // token group (2 tokens each)
  const int wv   = tid >> 6;
  const int lane = tid & 63;

  if (tid < NE) cf[tid] = 0.0f;
  __syncthreads();

  float psum[4] = {0.f, 0.f, 0.f, 0.f};
  float zc = 0.0f;
#pragma unroll
  for (int i = 0; i < 2; ++i) {
    const int t = blk * TM + 2 * ty + i;
    const float4 lv = *(const float4*)(part + (size_t)t * NE + 4 * tx);
    const float l0 = lv.x, l1 = lv.y, l2 = lv.z, l3 = lv.w;

    float m = fmaxf(fmaxf(l0, l1), fmaxf(l2, l3));
    m = fmaxf(m, __shfl_xor(m, 1));
    m = fmaxf(m, __shfl_xor(m, 2));
    m = fmaxf(m, __shfl_xor(m, 4));
    m = fmaxf(m, __shfl_xor(m, 8));
    const float e0 = expf(l0 - m), e1 = expf(l1 - m);
    const float e2 = expf(l2 - m), e3 = expf(l3 - m);
    float zs = (e0 + e1) + (e2 + e3);
    zs += __shfl_xor(zs, 1);
    zs += __shfl_xor(zs, 2);
    zs += __shfl_xor(zs, 4);
    zs += __shfl_xor(zs, 8);
    const float p0 = e0 / zs, p1 = e1 / zs, p2 = e2 / zs, p3 = e3 / zs;
    psum[0] += p0; psum[1] += p1; psum[2] += p2; psum[3] += p3;

    // local top-2 (ascending index => ties keep lower)
    float v1 = p0, v2 = p1; int i1 = 4 * tx, i2 = 4 * tx + 1;
    if (p1 > p0) { v1 = p1; i1 = 4 * tx + 1; v2 = p0; i2 = 4 * tx; }
    if (p2 > v1) { v2 = v1; i2 = i1; v1 = p2; i1 = 4 * tx + 2; }
    else if (p2 > v2) { v2 = p2; i2 = 4 * tx + 2; }
    if (p3 > v1) { v2 = v1; i2 = i1; v1 = p3; i1 = 4 * tx + 3; }
    else if (p3 > v2) { v2 = p3; i2 = 4 * tx + 3; }

    // butterfly merge across the 16 lanes of this token
#pragma unroll
    for (int s = 1; s <= 8; s <<= 1) {
      const float ov1 = __shfl_xor(v1, s); const int oi1 = __shfl_xor(i1, s);
      const float ov2 = __shfl_xor(v2, s); const int oi2 = __shfl_xor(i2, s);
      const bool o1 = (ov1 > v1) || (ov1 == v1 && oi1 < i1);
      if (o1) {
        const bool o2 = (ov2 > v1) || (ov2 == v1 && oi2 < i1);
        v2 = o2 ? ov2 : v1; i2 = o2 ? oi2 : i1;
        v1 = ov1; i1 = oi1;
      } else {
        const bool o2 = (ov1 > v2) || (ov1 == v2 && oi1 < i2);
        v2 = o2 ? ov1 : v2; i2 = o2 ? oi1 : i2;
      }
    }

    const float lz = m + logf(zs);
    if (tx == 0) {
      const float den = v1 + v2 + 1e-9f;
      out[2 * t]     = v1 / den;
      out[2 * t + 1] = v2 / den;
      out[2 * TT + 2 * t]     = (float)i1;
      out[2 * TT + 2 * t + 1] = (float)i2;
      atomicAdd(&cf[i1], 1.0f);
      atomicAdd(&cf[i2], 1.0f);
      zc += lz * lz;
    }
  }

#pragma unroll
  for (int j = 0; j < 4; ++j) {
    psum[j] += __shfl_xor(psum[j], 16);
    psum[j] += __shfl_xor(psum[j], 32);
  }
  if (lane < 16) {
#pragma unroll
    for (int j = 0; j < 4; ++j) psW[wv][4 * lane + j] = psum[j];
  }
  float z = zc;
#pragma unroll
  for (int s = 1; s <= 32; s <<= 1) z += __shfl_xor(z, s);
  if (lane == 0) zb[wv] = z;
  __syncthreads();

  if (tid < NE) {
    pP[blk * NE + tid] = psW[0][tid] + psW[1][tid] + psW[2][tid] + psW[3][tid];
    pC[blk * NE + tid] = cf[tid];
  }
  if (tid == 0) pZ[blk] = zb[0] + zb[1] + zb[2] + zb[3];
}

__global__ void router_final(const float* __restrict__ pP,
                             const float* __restrict__ pC,
                             const float* __restrict__ pZ,
                             float* __restrict__ out) {
  const int e = threadIdx.x;  // 64 threads = 1 wave
  float sP = 0.f, sC = 0.f;
  for (int b = 0; b < NBLK; ++b) {
    sP += pP[b * NE + e];
    sC += pC[b * NE + e];
  }
  const float f = sC * (1.0f / (TT * 2.0f));
  const float P = sP * (1.0f / (float)TT);
  out[4 * TT + 2 + e] = f;
  float term = f * P;
#pragma unroll
  for (int s = 1; s <= 32; s <<= 1) term += __shfl_xor(term, s);
  float zs = 0.f;
  for (int b = e; b < NBLK; b += NE) zs += pZ[b];
#pragma unroll
  for (int s = 1; s <= 32; s <<= 1) zs += __shfl_xor(zs, s);
  if (e == 0) {
    out[4 * TT]     = 0.01f * ((float)NE * term);
    out[4 * TT + 1] = 0.001f * (zs / (float)TT);
  }
}

// =====================================================================
// Fallback (validated round-1 fused kernel) for tiny ws_size.
// =====================================================================
__device__ __forceinline__ void async_copy16f(const float* src, float* dst) {
  async16((const void*)src, (void*)dst);
}

__launch_bounds__(256, 2)
__global__ void router_fused(const float* __restrict__ X,
                             const float* __restrict__ W,
                             float* __restrict__ out,
                             float* __restrict__ pP,
                             float* __restrict__ pC,
                             float* __restrict__ pZ) {
  __shared__ __align__(16) float sH[2][TM * 64];
  __shared__ __align__(16) float sW[2][NE * 64];
  __shared__ float psW[4][NE];
  __shared__ float cf[NE];
  __shared__ float zb[4];

  const int tid  = threadIdx.x;
  const int blk  = blockIdx.x;
  const int tx   = tid & 15;
  const int ty   = tid >> 4;
  const int wv   = tid >> 6;
  const int lane = tid & 63;

  if (tid < NE) cf[tid] = 0.0f;

  const int xoff = (tid & 15) << 4;
  const float* srcH[2];
  const float* srcW[4];
#pragma unroll
  for (int p = 0; p < 2; ++p) {
    const int r = ty + p * 16;
    const int sw = ((r >> 1) & 7) << 4;
    srcH[p] = X + (size_t)(blk * TM + r) * HD + ((xoff ^ sw) >> 2);
  }
#pragma unroll
  for (int p = 0; p < 4; ++p) {
    const int e = ty + p * 16;
    const int sw = ((e >> 2) & 7) << 4;
    srcW[p] = W + (size_t)e * HD + ((xoff ^ sw) >> 2);
  }

  auto stage = [&](int b, int kt) {
    const int o = kt * 64;
    float* dH = &sH[b][wv * 256];
    async_copy16f(srcH[0] + o, dH);
    async_copy16f(srcH[1] + o, dH + 1024);
    float* dW = &sW[b][wv * 256];
    async_copy16f(srcW[0] + o, dW);
    async_copy16f(srcW[1] + o, dW + 1024);
    async_copy16f(srcW[2] + o, dW + 2048);
    async_copy16f(srcW[3] + o, dW + 3072);
  };

  float acc[2][4] = {{0.f, 0.f, 0.f, 0.f}, {0.f, 0.f, 0.f, 0.f}};
  const int Hswz = (ty & 7) << 4;
  const int Wswz = (tx & 7) << 4;

  auto compute = [&](int b) {
    const char* hb = (const char*)(&sH[b][0]) + (ty << 9);
    const char* wb = (const char*)(&sW[b][0]) + (tx << 10);
#pragma unroll
    for (int h4 = 0; h4 < 16; ++h4) {
      const int oH = (h4 << 4) ^ Hswz;
      const int oW = (h4 << 4) ^ Wswz;
      const float4 h0 = *(const float4*)(hb + oH);
      const float4 h1 = *(const float4*)(hb + oH + 256);
      const float4 w0 = *(const float4*)(wb + oW);
      const float4 w1 = *(const float4*)(wb + oW + 256);
      const float4 w2 = *(const float4*)(wb + oW + 512);
      const float4 w3 = *(const float4*)(wb + oW + 768);
      FMA4(acc[0][0], h0, w0) FMA4(acc[0][1], h0, w1)
      FMA4(acc[0][2], h0, w2) FMA4(acc[0][3], h0, w3)
      FMA4(acc[1][0], h1, w0) FMA4(acc[1][1], h1, w1)
      FMA4(acc[1][2], h1, w2) FMA4(acc[1][3], h1, w3)
    }
  };

  int buf = 0;
  stage(0, 0);
  __syncthreads();
  for (int kt = 0; kt < 64; ++kt) {
    if (kt + 1 < 64) stage(buf ^ 1, kt + 1);
    compute(buf);
    __syncthreads();
    buf ^= 1;
  }

  float psum[4] = {0.f, 0.f, 0.f, 0.f};
  float zc = 0.0f;
#pragma unroll
  for (int i = 0; i < 2; ++i) {
    const float l0 = acc[i][0], l1 = acc[i][1], l2 = acc[i][2], l3 = acc[i][3];
    float m = fmaxf(fmaxf(l0, l1), fmaxf(l2, l3));
    m = fmaxf(m, __shfl_xor(m, 1));
    m = fmaxf(m, __shfl_xor(m, 2));
    m = fmaxf(m, __shfl_xor(m, 4));
    m = fmaxf(m, __shfl_xor(m, 8));
    const float e0 = expf(l0 - m), e1 = expf(l1 - m);
    const float e2 = expf(l2 - m), e3 = expf(l3 - m);
    float zs = (e0 + e1) + (e2 + e3);
    zs += __shfl_xor(zs, 1);
    zs += __shfl_xor(zs, 2);
    zs += __shfl_xor(zs, 4);
    zs += __shfl_xor(zs, 8);
    const float p0 = e0 / zs, p1 = e1 / zs, p2 = e2 / zs, p3 = e3 / zs;
    psum[0] += p0; psum[1] += p1; psum[2] += p2; psum[3] += p3;

    float v1 = p0, v2 = p1; int i1 = 4 * tx, i2 = 4 * tx + 1;
    if (p1 > p0) { v1 = p1; i1 = 4 * tx + 1; v2 = p0; i2 = 4 * tx; }
    if (p2 > v1) { v2 = v1; i2 = i1; v1 = p2; i1 = 4 * tx + 2; }
    else if (p2 > v2) { v2 = p2; i2 = 4 * tx + 2; }
    if (p3 > v1) { v2 = v1; i2 = i1; v1 = p3; i1 = 4 * tx + 3; }
    else if (p3 > v2) { v2 = p3; i2 = 4 * tx + 3; }

#pragma unroll
    for (int s = 1; s <= 8; s <<= 1) {
      const float ov1 = __shfl_xor(v1, s); const int oi1 = __shfl_xor(i1, s);
      const float ov2 = __shfl_xor(v2, s); const int oi2 = __shfl_xor(i2, s);
      const bool o1 = (ov1 > v1) || (ov1 == v1 && oi1 < i1);
      if (o1) {
        const bool o2 = (ov2 > v1) || (ov2 == v1 && oi2 < i1);
        v2 = o2 ? ov2 : v1; i2 = o2 ? oi2 : i1;
        v1 = ov1; i1 = oi1;
      } else {
        const bool o2 = (ov1 > v2) || (ov1 == v2 && oi1 < i2);
        v2 = o2 ? ov1 : v2; i2 = o2 ? oi1 : i2;
      }
    }

    const float lz = m + logf(zs);
    if (tx == 0) {
      const int t = blk * TM + 2 * ty + i;
      const float den = v1 + v2 + 1e-9f;
      out[2 * t]     = v1 / den;
      out[2 * t + 1] = v2 / den;
      out[2 * TT + 2 * t]     = (float)i1;
      out[2 * TT + 2 * t + 1] = (float)i2;
      atomicAdd(&cf[i1], 1.0f);
      atomicAdd(&cf[i2], 1.0f);
      zc += lz * lz;
    }
  }

#pragma unroll
  for (int j = 0; j < 4; ++j) {
    psum[j] += __shfl_xor(psum[j], 16);
    psum[j] += __shfl_xor(psum[j], 32);
  }
  if (lane < 16) {
#pragma unroll
    for (int j = 0; j < 4; ++j) psW[wv][4 * lane + j] = psum[j];
  }
  float z = zc;
#pragma unroll
  for (int s = 1; s <= 32; s <<= 1) z += __shfl_xor(z, s);
  if (lane == 0) zb[wv] = z;
  __syncthreads();

  if (tid < NE) {
    pP[blk * NE + tid] = psW[0][tid] + psW[1][tid] + psW[2][tid] + psW[3][tid];
    pC[blk * NE + tid] = cf[tid];
  }
  if (tid == 0) pZ[blk] = zb[0] + zb[1] + zb[2] + zb[3];
}

extern "C" void kernel_launch(void* const* d_in, const int* in_sizes, int n_in,
                              void* d_out, int out_size, void* d_ws, size_t ws_size,
                              hipStream_t stream) {
  const float* X = (const float*)d_in[0];   // [16384, 4096] f32
  const float* W = (const float*)d_in[1];   // [64, 4096] f32
  float* out = (float*)d_out;
  (void)in_sizes; (void)n_in; (void)out_size;

  // ws layout: WH, WL (ushort 64*4096 each), part (f32 TT*NE), pP, pC, pZ, flags
  const size_t WHALF = (size_t)NE * HD;                 // ushorts per plane
  const size_t PARTF = (size_t)TT * NE;                 // floats
  const size_t AUXF  = (size_t)NBLK * NE * 2 + NBLK;
  const size_t NEEDB = WHALF * 2 * sizeof(unsigned short) +
                       (PARTF + AUXF) * sizeof(float) + TT;

  if (ws_size >= NEEDB) {
    unsigned short* WH = (unsigned short*)d_ws;
    unsigned short* WL = WH + WHALF;
    float* part = (float*)(WL + WHALF);
    float* pP = part + PARTF;
    float* pC = pP + NBLK * NE;
    float* pZ = pC + NBLK * NE;
    unsigned char* flags = (unsigned char*)(pZ + NBLK);
    wconv<<<dim3(256), dim3(256), 0, stream>>>(W, WH, WL);
    gemm_mfma<<<dim3(NB5), dim3(256), 0, stream>>>(X, WH, WL, part);
    detect<<<dim3(TT / 256), dim3(256), 0, stream>>>(part, flags);
    fixup<<<dim3(TT / 64), dim3(256), 0, stream>>>(X, W, flags, part);
    router_epilogue<<<dim3(NBLK), dim3(256), 0, stream>>>(part, out, pP, pC, pZ);
    router_final<<<dim3(1), dim3(NE), 0, stream>>>(pP, pC, pZ, out);
  } else {
    float* pP = (float*)d_ws;
    float* pC = pP + NBLK * NE;
    float* pZ = pC + NBLK * NE;
    router_fused<<<dim3(NBLK), dim3(256), 0, stream>>>(X, W, out, pP, pC, pZ);
    router_final<<<dim3(1), dim3(NE), 0, stream>>>(pP, pC, pZ, out);
  }
}

// Round 7
// 259.599 us; speedup vs baseline: 2.0685x; 2.0685x over previous
//
#include <hip/hip_runtime.h>
#include <math.h>

#define TT 16384            // tokens
#define HD 4096             // hidden
#define NE 64               // experts
#define TM 32               // tokens per epilogue block
#define NBLK (TT / TM)      // 512 epilogue blocks
// ---- MFMA gemm geometry ----
#define TB5 32              // tokens per block
#define NB5 (TT / TB5)      // 512 blocks (2 per CU)
#define BK5 64              // h per staged tile
#define NKT5 (HD / BK5)     // 64 k-iterations
#define TAU 1e-5f           // near-tie fixup threshold (prob units)

typedef __attribute__((ext_vector_type(8))) short s8v;   // 8 x bf16
typedef __attribute__((ext_vector_type(4))) float f4v;   // MFMA acc

// ---- async global->LDS: dest wave-uniform base; HW adds lane*16 ----
__device__ __forceinline__ void async16(const void* src, void* dst) {
  __builtin_amdgcn_global_load_lds(
      (const __attribute__((address_space(1))) void*)src,
      (__attribute__((address_space(3))) void*)dst, 16, 0, 0);
}

#define FMA4(A, HV, WV)                                       \
  A = fmaf((HV).x, (WV).x, A); A = fmaf((HV).y, (WV).y, A);   \
  A = fmaf((HV).z, (WV).z, A); A = fmaf((HV).w, (WV).w, A);

// RNE float->bf16 (bit trick; inputs are normal randoms, no NaN)
__device__ __forceinline__ unsigned short f2bf(float f) {
  unsigned int u = __float_as_uint(f);
  return (unsigned short)((u + 0x7FFFu + ((u >> 16) & 1u)) >> 16);
}
__device__ __forceinline__ float bf2f(unsigned short h) {
  return __uint_as_float(((unsigned int)h) << 16);
}

__device__ __forceinline__ void split8(float4 a, float4 b, s8v& hi, s8v& lo) {
  float v[8] = {a.x, a.y, a.z, a.w, b.x, b.y, b.z, b.w};
#pragma unroll
  for (int i = 0; i < 8; ++i) {
    unsigned short h = f2bf(v[i]);
    unsigned short l = f2bf(v[i] - bf2f(h));
    hi[i] = (short)h; lo[i] = (short)l;
  }
}

// =====================================================================
// Kernel 0: W fp32 -> bf16 hi/lo planes in workspace.
// =====================================================================
__global__ void wconv(const float* __restrict__ W,
                      unsigned short* __restrict__ WH,
                      unsigned short* __restrict__ WL) {
  const int i = blockIdx.x * 256 + threadIdx.x;   // 65536 float4 groups
  const float4 v = *(const float4*)(W + (size_t)i * 4);
  float x[4] = {v.x, v.y, v.z, v.w};
#pragma unroll
  for (int j = 0; j < 4; ++j) {
    unsigned short h = f2bf(x[j]);
    WH[(size_t)i * 4 + j] = h;
    WL[(size_t)i * 4 + j] = f2bf(x[j] - bf2f(h));
  }
}

// =====================================================================
// Kernel 1: bf16x3 MFMA GEMM, logits -> part[t][e] fp32. (R5-validated,
// unchanged.)
// =====================================================================
__launch_bounds__(256, 2)
__global__ void gemm_mfma(const float* __restrict__ X,
                          const unsigned short* __restrict__ WH,
                          const unsigned short* __restrict__ WL,
                          float* __restrict__ part) {
  __shared__ __align__(16) float          sX[2][TB5 * BK5];  // 2 x 8 KB
  __shared__ __align__(16) unsigned short sH[2][NE * BK5];   // 2 x 8 KB
  __shared__ __align__(16) unsigned short sL[2][NE * BK5];   // 2 x 8 KB

  const int tid  = threadIdx.x;
  const int lane = tid & 63;
  const int w    = tid >> 6;
  const int t0   = blockIdx.x * TB5;

  const float* srcX[2];
#pragma unroll
  for (int ih = 0; ih < 2; ++ih) {
    const int row = w * 8 + ih * 4 + (lane >> 4);
    const int key = (ih * 4 + (lane >> 4)) & 7;          // row & 7
    const int c   = (lane & 15) ^ key;
    srcX[ih] = X + (size_t)(t0 + row) * HD + c * 4;
  }
  const unsigned short* srcH[2];
  const unsigned short* srcL[2];
#pragma unroll
  for (int ih = 0; ih < 2; ++ih) {
    const int e = w * 16 + ih * 8 + (lane >> 3);
    const int c = (lane & 7) ^ (lane >> 3);              // key = e & 7
    srcH[ih] = WH + (size_t)e * HD + c * 8;
    srcL[ih] = WL + (size_t)e * HD + c * 8;
  }

  auto stage = [&](int b, int kt) {
    const int o = kt * BK5;
#pragma unroll
    for (int ih = 0; ih < 2; ++ih)
      async16(srcX[ih] + o, &sX[b][(w * 8 + ih * 4) * BK5]);
#pragma unroll
    for (int ih = 0; ih < 2; ++ih)
      async16(srcH[ih] + o, &sH[b][(w * 16 + ih * 8) * BK5]);
#pragma unroll
    for (int ih = 0; ih < 2; ++ih)
      async16(srcL[ih] + o, &sL[b][(w * 16 + ih * 8) * BK5]);
  };

  const int fr    = lane & 15;
  const int fq    = lane >> 4;
  const int tloc  = (w >> 1) * 16 + fr;   // A-frag token row in block
  const int keyA  = fr & 7;               // tloc & 7
  const int ebase = (w & 1) * 32;

  f4v acc[2];
  acc[0] = (f4v)(0.0f); acc[1] = (f4v)(0.0f);

  int buf = 0;
  stage(0, 0);
  __syncthreads();
  for (int kt = 0; kt < NKT5; ++kt) {
    if (kt + 1 < NKT5) stage(buf ^ 1, kt + 1);
#pragma unroll
    for (int ks = 0; ks < 2; ++ks) {
      const int c0 = fq * 2 + ks * 8;
      const float4 xa = *(const float4*)(&sX[buf][tloc * BK5 + (((c0)     ^ keyA) << 2)]);
      const float4 xb = *(const float4*)(&sX[buf][tloc * BK5 + (((c0 + 1) ^ keyA) << 2)]);
      s8v ah, al;
      split8(xa, xb, ah, al);
#pragma unroll
      for (int nf = 0; nf < 2; ++nf) {
        const int eg = ebase + nf * 16 + fr;
        const int c  = (fq + ks * 4) ^ (eg & 7);
        const s8v bh = *(const s8v*)(&sH[buf][eg * BK5 + c * 8]);
        const s8v bl = *(const s8v*)(&sL[buf][eg * BK5 + c * 8]);
        acc[nf] = __builtin_amdgcn_mfma_f32_16x16x32_bf16(ah, bh, acc[nf], 0, 0, 0);
        acc[nf] = __builtin_amdgcn_mfma_f32_16x16x32_bf16(ah, bl, acc[nf], 0, 0, 0);
        acc[nf] = __builtin_amdgcn_mfma_f32_16x16x32_bf16(al, bh, acc[nf], 0, 0, 0);
      }
    }
    __syncthreads();
    buf ^= 1;
  }

#pragma unroll
  for (int nf = 0; nf < 2; ++nf) {
    const int e = ebase + nf * 16 + fr;
#pragma unroll
    for (int i = 0; i < 4; ++i) {
      const int t = t0 + (w >> 1) * 16 + fq * 4 + i;
      part[(size_t)t * NE + e] = acc[nf][i];
    }
  }
}

// =====================================================================
// Kernel 2: detect — compact near-tie tokens (top-2/3 prob gap < TAU)
// into a worklist. List order is nondeterministic but fixup results are
// per-token and order-independent -> deterministic output.
// =====================================================================
__global__ void detect(const float* __restrict__ part,
                       int* __restrict__ nFlag,
                       int* __restrict__ list) {
  const int t = blockIdx.x * 256 + threadIdx.x;
  const float* pr = part + (size_t)t * NE;
  float l[NE];
  float m = -1e30f;
#pragma unroll
  for (int i = 0; i < 16; ++i) {
    const float4 v = *(const float4*)(pr + 4 * i);
    l[4 * i] = v.x; l[4 * i + 1] = v.y; l[4 * i + 2] = v.z; l[4 * i + 3] = v.w;
    m = fmaxf(m, fmaxf(fmaxf(v.x, v.y), fmaxf(v.z, v.w)));
  }
  float zs = 0.0f;
#pragma unroll
  for (int i = 0; i < NE; ++i) { l[i] = expf(l[i] - m); zs += l[i]; }
  float v1 = -1.0f, v2 = -1.0f, v3 = -1.0f;
#pragma unroll
  for (int i = 0; i < NE; ++i) {
    const float p = l[i];
    if (p > v1)      { v3 = v2; v2 = v1; v1 = p; }
    else if (p > v2) { v3 = v2; v2 = p; }
    else if (p > v3) { v3 = p; }
  }
  const float thr = TAU * zs;
  if (((v1 - v2) < thr) || ((v2 - v3) < thr)) {
    const int k = atomicAdd(nFlag, 1);
    list[k] = t;
  }
}

// =====================================================================
// Kernel 3: fixup — strided worklist; ~1 token per block. Per-token
// summation semantics byte-identical to R5/R6-validated path:
// thread = (e, q), serial ascending 1024-elem quarter, fixed 4-way
// combine. No launch-bounds clamp (VGPR-rich -> deep load pipelining).
// =====================================================================
__global__ void fixup(const float* __restrict__ X,
                      const float* __restrict__ W,
                      const int* __restrict__ nFlag,
                      const int* __restrict__ list,
                      float* __restrict__ part) {
  __shared__ float red[NE][4];
  const int tid = threadIdx.x;
  const int e   = tid >> 2;
  const int q   = tid & 3;
  const int n   = *nFlag;

  for (int idx = blockIdx.x; idx < n; idx += gridDim.x) {
    const int t = list[idx];
    const float* xr = X + (size_t)t * HD + q * 1024;
    const float* wr = W + (size_t)e * HD + q * 1024;
    float s = 0.0f;
    for (int h = 0; h < 1024; h += 4) {
      const float4 xv = *(const float4*)(xr + h);
      const float4 wv = *(const float4*)(wr + h);
      FMA4(s, xv, wv)
    }
    red[e][q] = s;
    __syncthreads();
    if (q == 0)
      part[(size_t)t * NE + e] = (red[e][0] + red[e][1]) + (red[e][2] + red[e][3]);
    __syncthreads();
  }
}

// =====================================================================
// Kernel 4: epilogue — validated R1 softmax/top-2/renorm/loss partials,
// reading (corrected) part directly.
// =====================================================================
__global__ void router_epilogue(const float* __restrict__ part,
                                float* __restrict__ out,
                                float* __restrict__ pP,
                                float* __restrict__ pC,
                                float* __restrict__ pZ) {
  __shared__ float psW[4][NE];
  __shared__ float cf[NE];
  __shared__ float zb[4];

  const int tid  = threadIdx.x;
  const int blk  = blockIdx.x;
  const int tx   = tid & 15;   // expert group (4 experts each)
  const int ty   = tid >> 4;   // token group (2 tokens each)
  const int wv   = tid >> 6;
  const int lane = tid & 63;

  if (tid < NE) cf[tid] = 0.0f;
  __syncthreads();

  float psum[4] = {0.f, 0.f, 0.f, 0.f};
  float zc = 0.0f;
#pragma unroll
  for (int i = 0; i < 2; ++i) {
    const int t = blk * TM + 2 * ty + i;
    const float4 lv = *(const float4*)(part + (size_t)t * NE + 4 * tx);
    const float l0 = lv.x, l1 = lv.y, l2 = lv.z, l3 = lv.w;

    float m = fmaxf(fmaxf(l0, l1), fmaxf(l2, l3));
    m = fmaxf(m, __shfl_xor(m, 1));
    m = fmaxf(m, __shfl_xor(m, 2));
    m = fmaxf(m, __shfl_xor(m, 4));
    m = fmaxf(m, __shfl_xor(m, 8));
    const float e0 = expf(l0 - m), e1 = expf(l1 - m);
    const float e2 = expf(l2 - m), e3 = expf(l3 - m);
    float zs = (e0 + e1) + (e2 + e3);
    zs += __shfl_xor(zs, 1);
    zs += __shfl_xor(zs, 2);
    zs += __shfl_xor(zs, 4);
    zs += __shfl_xor(zs, 8);
    const float p0 = e0 / zs, p1 = e1 / zs, p2 = e2 / zs, p3 = e3 / zs;
    psum[0] += p0; psum[1] += p1; psum[2] += p2; psum[3] += p3;

    // local top-2 (ascending index => ties keep lower)
    float v1 = p0, v2 = p1; int i1 = 4 * tx, i2 = 4 * tx + 1;
    if (p1 > p0) { v1 = p1; i1 = 4 * tx + 1; v2 = p0; i2 = 4 * tx; }
    if (p2 > v1) { v2 = v1; i2 = i1; v1 = p2; i1 = 4 * tx + 2; }
    else if (p2 > v2) { v2 = p2; i2 = 4 * tx + 2; }
    if (p3 > v1) { v2 = v1; i2 = i1; v1 = p3; i1 = 4 * tx + 3; }
    else if (p3 > v2) { v2 = p3; i2 = 4 * tx + 3; }

    // butterfly merge across the 16 lanes of this token
#pragma unroll
    for (int s = 1; s <= 8; s <<= 1) {
      const float ov1 = __shfl_xor(v1, s); const int oi1 = __shfl_xor(i1, s);
      const float ov2 = __shfl_xor(v2, s); const int oi2 = __shfl_xor(i2, s);
      const bool o1 = (ov1 > v1) || (ov1 == v1 && oi1 < i1);
      if (o1) {
        const bool o2 = (ov2 > v1) || (ov2 == v1 && oi2 < i1);
        v2 = o2 ? ov2 : v1; i2 = o2 ? oi2 : i1;
        v1 = ov1; i1 = oi1;
      } else {
        const bool o2 = (ov1 > v2) || (ov1 == v2 && oi1 < i2);
        v2 = o2 ? ov1 : v2; i2 = o2 ? oi1 : i2;
      }
    }

    const float lz = m + logf(zs);
    if (tx == 0) {
      const float den = v1 + v2 + 1e-9f;
      out[2 * t]     = v1 / den;
      out[2 * t + 1] = v2 / den;
      out[2 * TT + 2 * t]     = (float)i1;
      out[2 * TT + 2 * t + 1] = (float)i2;
      atomicAdd(&cf[i1], 1.0f);
      atomicAdd(&cf[i2], 1.0f);
      zc += lz * lz;
    }
  }

#pragma unroll
  for (int j = 0; j < 4; ++j) {
    psum[j] += __shfl_xor(psum[j], 16);
    psum[j] += __shfl_xor(psum[j], 32);
  }
  if (lane < 16) {
#pragma unroll
    for (int j = 0; j < 4; ++j) psW[wv][4 * lane + j] = psum[j];
  }
  float z = zc;
#pragma unroll
  for (int s = 1; s <= 32; s <<= 1) z += __shfl_xor(z, s);
  if (lane == 0) zb[wv] = z;
  __syncthreads();

  if (tid < NE) {
    pP[blk * NE + tid] = psW[0][tid] + psW[1][tid] + psW[2][tid] + psW[3][tid];
    pC[blk * NE + tid] = cf[tid];
  }
  if (tid == 0) pZ[blk] = zb[0] + zb[1] + zb[2] + zb[3];
}

__global__ void router_final(const float* __restrict__ pP,
                             const float* __restrict__ pC,
                             const float* __restrict__ pZ,
                             float* __restrict__ out) {
  const int e = threadIdx.x;  // 64 threads = 1 wave
  float sP = 0.f, sC = 0.f;
  for (int b = 0; b < NBLK; ++b) {
    sP += pP[b * NE + e];
    sC += pC[b * NE + e];
  }
  const float f = sC * (1.0f / (TT * 2.0f));
  const float P = sP * (1.0f / (float)TT);
  out[4 * TT + 2 + e] = f;
  float term = f * P;
#pragma unroll
  for (int s = 1; s <= 32; s <<= 1) term += __shfl_xor(term, s);
  float zs = 0.f;
  for (int b = e; b < NBLK; b += NE) zs += pZ[b];
#pragma unroll
  for (int s = 1; s <= 32; s <<= 1) zs += __shfl_xor(zs, s);
  if (e == 0) {
    out[4 * TT]     = 0.01f * ((float)NE * term);
    out[4 * TT + 1] = 0.001f * (zs / (float)TT);
  }
}

// =====================================================================
// Fallback (validated round-1 fused kernel) for tiny ws_size.
// =====================================================================
__device__ __forceinline__ void async_copy16f(const float* src, float* dst) {
  async16((const void*)src, (void*)dst);
}

__launch_bounds__(256, 2)
__global__ void router_fused(const float* __restrict__ X,
                             const float* __restrict__ W,
                             float* __restrict__ out,
                             float* __restrict__ pP,
                             float* __restrict__ pC,
                             float* __restrict__ pZ) {
  __shared__ __align__(16) float sH[2][TM * 64];
  __shared__ __align__(16) float sW[2][NE * 64];
  __shared__ float psW[4][NE];
  __shared__ float cf[NE];
  __shared__ float zb[4];

  const int tid  = threadIdx.x;
  const int blk  = blockIdx.x;
  const int tx   = tid & 15;
  const int ty   = tid >> 4;
  const int wv   = tid >> 6;
  const int lane = tid & 63;

  if (tid < NE) cf[tid] = 0.0f;

  const int xoff = (tid & 15) << 4;
  const float* srcH[2];
  const float* srcW[4];
#pragma unroll
  for (int p = 0; p < 2; ++p) {
    const int r = ty + p * 16;
    const int sw = ((r >> 1) & 7) << 4;
    srcH[p] = X + (size_t)(blk * TM + r) * HD + ((xoff ^ sw) >> 2);
  }
#pragma unroll
  for (int p = 0; p < 4; ++p) {
    const int e = ty + p * 16;
    const int sw = ((e >> 2) & 7) << 4;
    srcW[p] = W + (size_t)e * HD + ((xoff ^ sw) >> 2);
  }

  auto stage = [&](int b, int kt) {
    const int o = kt * 64;
    float* dH = &sH[b][wv * 256];
    async_copy16f(srcH[0] + o, dH);
    async_copy16f(srcH[1] + o, dH + 1024);
    float* dW = &sW[b][wv * 256];
    async_copy16f(srcW[0] + o, dW);
    async_copy16f(srcW[1] + o, dW + 1024);
    async_copy16f(srcW[2] + o, dW + 2048);
    async_copy16f(srcW[3] + o, dW + 3072);
  };

  float acc[2][4] = {{0.f, 0.f, 0.f, 0.f}, {0.f, 0.f, 0.f, 0.f}};
  const int Hswz = (ty & 7) << 4;
  const int Wswz = (tx & 7) << 4;

  auto compute = [&](int b) {
    const char* hb = (const char*)(&sH[b][0]) + (ty << 9);
    const char* wb = (const char*)(&sW[b][0]) + (tx << 10);
#pragma unroll
    for (int h4 = 0; h4 < 16; ++h4) {
      const int oH = (h4 << 4) ^ Hswz;
      const int oW = (h4 << 4) ^ Wswz;
      const float4 h0 = *(const float4*)(hb + oH);
      const float4 h1 = *(const float4*)(hb + oH + 256);
      const float4 w0 = *(const float4*)(wb + oW);
      const float4 w1 = *(const float4*)(wb + oW + 256);
      const float4 w2 = *(const float4*)(wb + oW + 512);
      const float4 w3 = *(const float4*)(wb + oW + 768);
      FMA4(acc[0][0], h0, w0) FMA4(acc[0][1], h0, w1)
      FMA4(acc[0][2], h0, w2) FMA4(acc[0][3], h0, w3)
      FMA4(acc[1][0], h1, w0) FMA4(acc[1][1], h1, w1)
      FMA4(acc[1][2], h1, w2) FMA4(acc[1][3], h1, w3)
    }
  };

  int buf = 0;
  stage(0, 0);
  __syncthreads();
  for (int kt = 0; kt < 64; ++kt) {
    if (kt + 1 < 64) stage(buf ^ 1, kt + 1);
    compute(buf);
    __syncthreads();
    buf ^= 1;
  }

  float psum[4] = {0.f, 0.f, 0.f, 0.f};
  float zc = 0.0f;
#pragma unroll
  for (int i = 0; i < 2; ++i) {
    const float l0 = acc[i][0], l1 = acc[i][1], l2 = acc[i][2], l3 = acc[i][3];
    float m = fmaxf(fmaxf(l0, l1), fmaxf(l2, l3));
    m = fmaxf(m, __shfl_xor(m, 1));
    m = fmaxf(m, __shfl_xor(m, 2));
    m = fmaxf(m, __shfl_xor(m, 4));
    m = fmaxf(m, __shfl_xor(m, 8));
    const float e0 = expf(l0 - m), e1 = expf(l1 - m);
    const float e2 = expf(l2 - m), e3 = expf(l3 - m);
    float zs = (e0 + e1) + (e2 + e3);
    zs += __shfl_xor(zs, 1);
    zs += __shfl_xor(zs, 2);
    zs += __shfl_xor(zs, 4);
    zs += __shfl_xor(zs, 8);
    const float p0 = e0 / zs, p1 = e1 / zs, p2 = e2 / zs, p3 = e3 / zs;
    psum[0] += p0; psum[1] += p1; psum[2] += p2; psum[3] += p3;

    float v1 = p0, v2 = p1; int i1 = 4 * tx, i2 = 4 * tx + 1;
    if (p1 > p0) { v1 = p1; i1 = 4 * tx + 1; v2 = p0; i2 = 4 * tx; }
    if (p2 > v1) { v2 = v1; i2 = i1; v1 = p2; i1 = 4 * tx + 2; }
    else if (p2 > v2) { v2 = p2; i2 = 4 * tx + 2; }
    if (p3 > v1) { v2 = v1; i2 = i1; v1 = p3; i1 = 4 * tx + 3; }
    else if (p3 > v2) { v2 = p3; i2 = 4 * tx + 3; }

#pragma unroll
    for (int s = 1; s <= 8; s <<= 1) {
      const float ov1 = __shfl_xor(v1, s); const int oi1 = __shfl_xor(i1, s);
      const float ov2 = __shfl_xor(v2, s); const int oi2 = __shfl_xor(i2, s);
      const bool o1 = (ov1 > v1) || (ov1 == v1 && oi1 < i1);
      if (o1) {
        const bool o2 = (ov2 > v1) || (ov2 == v1 && oi2 < i1);
        v2 = o2 ? ov2 : v1; i2 = o2 ? oi2 : i1;
        v1 = ov1; i1 = oi1;
      } else {
        const bool o2 = (ov1 > v2) || (ov1 == v2 && oi1 < i2);
        v2 = o2 ? ov1 : v2; i2 = o2 ? oi1 : i2;
      }
    }

    const float lz = m + logf(zs);
    if (tx == 0) {
      const int t = blk * TM + 2 * ty + i;
      const float den = v1 + v2 + 1e-9f;
      out[2 * t]     = v1 / den;
      out[2 * t + 1] = v2 / den;
      out[2 * TT + 2 * t]     = (float)i1;
      out[2 * TT + 2 * t + 1] = (float)i2;
      atomicAdd(&cf[i1], 1.0f);
      atomicAdd(&cf[i2], 1.0f);
      zc += lz * lz;
    }
  }

#pragma unroll
  for (int j = 0; j < 4; ++j) {
    psum[j] += __shfl_xor(psum[j], 16);
    psum[j] += __shfl_xor(psum[j], 32);
  }
  if (lane < 16) {
#pragma unroll
    for (int j = 0; j < 4; ++j) psW[wv][4 * lane + j] = psum[j];
  }
  float z = zc;
#pragma unroll
  for (int s = 1; s <= 32; s <<= 1) z += __shfl_xor(z, s);
  if (lane == 0) zb[wv] = z;
  __syncthreads();

  if (tid < NE) {
    pP[blk * NE + tid] = psW[0][tid] + psW[1][tid] + psW[2][tid] + psW[3][tid];
    pC[blk * NE + tid] = cf[tid];
  }
  if (tid == 0) pZ[blk] = zb[0] + zb[1] + zb[2] + zb[3];
}

extern "C" void kernel_launch(void* const* d_in, const int* in_sizes, int n_in,
                              void* d_out, int out_size, void* d_ws, size_t ws_size,
                              hipStream_t stream) {
  const float* X = (const float*)d_in[0];   // [16384, 4096] f32
  const float* W = (const float*)d_in[1];   // [64, 4096] f32
  float* out = (float*)d_out;
  (void)in_sizes; (void)n_in; (void)out_size;

  // ws layout: WH, WL (ushort 64*4096 each), part (f32 TT*NE), pP, pC, pZ,
  //            nFlag (int), list (int TT)
  const size_t WHALF = (size_t)NE * HD;                 // ushorts per plane
  const size_t PARTF = (size_t)TT * NE;                 // floats
  const size_t AUXF  = (size_t)NBLK * NE * 2 + NBLK;
  const size_t NEEDB = WHALF * 2 * sizeof(unsigned short) +
                       (PARTF + AUXF) * sizeof(float) +
                       (1 + TT) * sizeof(int);

  if (ws_size >= NEEDB) {
    unsigned short* WH = (unsigned short*)d_ws;
    unsigned short* WL = WH + WHALF;
    float* part = (float*)(WL + WHALF);
    float* pP = part + PARTF;
    float* pC = pP + NBLK * NE;
    float* pZ = pC + NBLK * NE;
    int* nFlag = (int*)(pZ + NBLK);
    int* list  = nFlag + 1;
    hipMemsetAsync(nFlag, 0, sizeof(int), stream);
    wconv<<<dim3(256), dim3(256), 0, stream>>>(W, WH, WL);
    gemm_mfma<<<dim3(NB5), dim3(256), 0, stream>>>(X, WH, WL, part);
    detect<<<dim3(TT / 256), dim3(256), 0, stream>>>(part, nFlag, list);
    fixup<<<dim3(512), dim3(256), 0, stream>>>(X, W, nFlag, list, part);
    router_epilogue<<<dim3(NBLK), dim3(256), 0, stream>>>(part, out, pP, pC, pZ);
    router_final<<<dim3(1), dim3(NE), 0, stream>>>(pP, pC, pZ, out);
  } else {
    float* pP = (float*)d_ws;
    float* pC = pP + NBLK * NE;
    float* pZ = pC + NBLK * NE;
    router_fused<<<dim3(NBLK), dim3(256), 0, stream>>>(X, W, out, pP, pC, pZ);
    router_final<<<dim3(1), dim3(NE), 0, stream>>>(pP, pC, pZ, out);
  }
}

// Round 8
// 236.349 us; speedup vs baseline: 2.2720x; 1.0984x over previous
//
#include <hip/hip_runtime.h>
#include <math.h>

#define TT 16384            // tokens
#define HD 4096             // hidden
#define NE 64               // experts
#define TM 32               // tokens per epilogue block
#define NBLK (TT / TM)      // 512 epilogue blocks
#define TAU 1e-5f           // near-tie fixup threshold (prob units)
// ---- gemm_v6 geometry ----
#define KSP 4               // split-K
#define HSP6 (HD / KSP)     // 1024 h per split
#define T6 64               // tokens per block
#define NTB6 (TT / T6)      // 256 token-blocks (x4 kz = 1024 blocks, 4/CU)
#define BK6 32              // h per staged tile
#define NKT6 (HSP6 / BK6)   // 32 k-iterations

typedef __attribute__((ext_vector_type(8))) short s8v;   // 8 x bf16
typedef __attribute__((ext_vector_type(4))) float f4v;   // MFMA acc

// ---- async global->LDS: dest wave-uniform base; HW adds lane*16 ----
__device__ __forceinline__ void async16(const void* src, void* dst) {
  __builtin_amdgcn_global_load_lds(
      (const __attribute__((address_space(1))) void*)src,
      (__attribute__((address_space(3))) void*)dst, 16, 0, 0);
}

#define FMA4(A, HV, WV)                                       \
  A = fmaf((HV).x, (WV).x, A); A = fmaf((HV).y, (WV).y, A);   \
  A = fmaf((HV).z, (WV).z, A); A = fmaf((HV).w, (WV).w, A);

// RNE float->bf16 (bit trick; inputs are normal randoms, no NaN)
__device__ __forceinline__ unsigned short f2bf(float f) {
  unsigned int u = __float_as_uint(f);
  return (unsigned short)((u + 0x7FFFu + ((u >> 16) & 1u)) >> 16);
}
__device__ __forceinline__ float bf2f(unsigned short h) {
  return __uint_as_float(((unsigned int)h) << 16);
}

__device__ __forceinline__ void split8(float4 a, float4 b, s8v& hi, s8v& lo) {
  float v[8] = {a.x, a.y, a.z, a.w, b.x, b.y, b.z, b.w};
#pragma unroll
  for (int i = 0; i < 8; ++i) {
    unsigned short h = f2bf(v[i]);
    unsigned short l = f2bf(v[i] - bf2f(h));
    hi[i] = (short)h; lo[i] = (short)l;
  }
}

// =====================================================================
// Kernel 0: W fp32 -> bf16 hi/lo planes in workspace. (R5-validated.)
// =====================================================================
__global__ void wconv(const float* __restrict__ W,
                      unsigned short* __restrict__ WH,
                      unsigned short* __restrict__ WL) {
  const int i = blockIdx.x * 256 + threadIdx.x;   // 65536 float4 groups
  const float4 v = *(const float4*)(W + (size_t)i * 4);
  float x[4] = {v.x, v.y, v.z, v.w};
#pragma unroll
  for (int j = 0; j < 4; ++j) {
    unsigned short h = f2bf(x[j]);
    WH[(size_t)i * 4 + j] = h;
    WL[(size_t)i * 4 + j] = f2bf(x[j] - bf2f(h));
  }
}

// =====================================================================
// Kernel 1: gemm_v6 — bf16x3 MFMA split-K GEMM.
// Grid 1024 = 256 token-blocks x 4 kz; 256 thr = 4 waves; 4 blocks/CU.
// Wave w = (m-group w>>1, n-group w&1): 32 tokens x 32 experts as
// 2x2 16x16 frags. LDS: bf16 hi/lo planes for X (reg-staged, converted
// once per element) and W (pre-converted, global_load_lds w/ pre-swizzled
// source). Swizzle: phys_chunk = chunk ^ ((row>>1)&3), rows 32 bf16
// (4 chunks of 16B) -> all 16-lane phases <=2-way (free) on read+write.
// =====================================================================
__launch_bounds__(256, 4)
__global__ void gemm_v6(const float* __restrict__ X,
                        const unsigned short* __restrict__ WH,
                        const unsigned short* __restrict__ WL,
                        float* __restrict__ part) {
  __shared__ __align__(16) unsigned short sXH[2][T6 * BK6];  // 4 KB each
  __shared__ __align__(16) unsigned short sXL[2][T6 * BK6];
  __shared__ __align__(16) unsigned short sWH[2][NE * BK6];
  __shared__ __align__(16) unsigned short sWL[2][NE * BK6];

  const int tid  = threadIdx.x;
  const int lane = tid & 63;
  const int w    = tid >> 6;
  const int tb   = blockIdx.x & (NTB6 - 1);
  const int kz   = blockIdx.x >> 8;          // NTB6 == 256
  const int t0   = tb * T6;
  const int h0   = kz * HSP6;

  // ---- X reg-staging source: thread (row xr, bf16-chunk xc = 8 h) ----
  const int xr = tid >> 2;                   // token row 0..63
  const int xc = tid & 3;                    // chunk 0..3
  const float* xsrc = X + (size_t)(t0 + xr) * HD + h0 + xc * 8;
  const int xwoff = xr * BK6 + ((xc ^ ((xr >> 1) & 3)) << 3);  // LDS elem off

  // ---- W async sources (pre-swizzled logical chunk per lane) ----
  const int wrow = w * 16 + (lane >> 2);     // expert row
  const int wlc  = (lane & 3) ^ ((lane >> 3) & 3);  // logical chunk
  const unsigned short* wsrcH = WH + (size_t)wrow * HD + h0 + wlc * 8;
  const unsigned short* wsrcL = WL + (size_t)wrow * HD + h0 + wlc * 8;

  const int fr = lane & 15;
  const int fq = lane >> 4;

  f4v acc[2][2];
#pragma unroll
  for (int mf = 0; mf < 2; ++mf)
#pragma unroll
    for (int nf = 0; nf < 2; ++nf) acc[mf][nf] = (f4v)(0.0f);

  // ---- prologue: stage tile 0 ----
  float4 xa = *(const float4*)(xsrc);
  float4 xb = *(const float4*)(xsrc + 4);
  async16(wsrcH, &sWH[0][w * 512]);
  async16(wsrcL, &sWL[0][w * 512]);
  {
    s8v hi, lo;
    split8(xa, xb, hi, lo);
    *(s8v*)&sXH[0][xwoff] = hi;
    *(s8v*)&sXL[0][xwoff] = lo;
  }
  __syncthreads();

  int buf = 0;
  for (int kt = 0; kt < NKT6; ++kt) {
    const bool more = (kt + 1 < NKT6);
    if (more) {
      const int o = (kt + 1) * BK6;
      xa = *(const float4*)(xsrc + o);
      xb = *(const float4*)(xsrc + o + 4);
      async16(wsrcH + o, &sWH[buf ^ 1][w * 512]);
      async16(wsrcL + o, &sWL[buf ^ 1][w * 512]);
    }

    // ---- compute current buffer: 8 ds_read_b128 + 12 MFMA per wave ----
    s8v ah[2], al[2], bh[2], bl[2];
#pragma unroll
    for (int mf = 0; mf < 2; ++mf) {
      const int row = (w >> 1) * 32 + mf * 16 + fr;
      const int off = row * BK6 + ((fq ^ ((row >> 1) & 3)) << 3);
      ah[mf] = *(const s8v*)&sXH[buf][off];
      al[mf] = *(const s8v*)&sXL[buf][off];
    }
#pragma unroll
    for (int nf = 0; nf < 2; ++nf) {
      const int row = (w & 1) * 32 + nf * 16 + fr;
      const int off = row * BK6 + ((fq ^ ((row >> 1) & 3)) << 3);
      bh[nf] = *(const s8v*)&sWH[buf][off];
      bl[nf] = *(const s8v*)&sWL[buf][off];
    }
#pragma unroll
    for (int mf = 0; mf < 2; ++mf)
#pragma unroll
      for (int nf = 0; nf < 2; ++nf) {
        acc[mf][nf] = __builtin_amdgcn_mfma_f32_16x16x32_bf16(ah[mf], bh[nf], acc[mf][nf], 0, 0, 0);
        acc[mf][nf] = __builtin_amdgcn_mfma_f32_16x16x32_bf16(ah[mf], bl[nf], acc[mf][nf], 0, 0, 0);
        acc[mf][nf] = __builtin_amdgcn_mfma_f32_16x16x32_bf16(al[mf], bh[nf], acc[mf][nf], 0, 0, 0);
      }

    if (more) {
      s8v hi, lo;
      split8(xa, xb, hi, lo);
      *(s8v*)&sXH[buf ^ 1][xwoff] = hi;
      *(s8v*)&sXL[buf ^ 1][xwoff] = lo;
    }
    __syncthreads();
    buf ^= 1;
  }

  // ---- write partials: D col = fr (expert), row = fq*4+i (token) ----
#pragma unroll
  for (int mf = 0; mf < 2; ++mf)
#pragma unroll
    for (int nf = 0; nf < 2; ++nf) {
      const int e = (w & 1) * 32 + nf * 16 + fr;
#pragma unroll
      for (int i = 0; i < 4; ++i) {
        const int t = t0 + (w >> 1) * 32 + mf * 16 + fq * 4 + i;
        part[((size_t)kz * TT + t) * NE + e] = acc[mf][nf][i];
      }
    }
}

// =====================================================================
// Kernel 2: reduce_detect — sum 4 split-K partials -> logits, then the
// R7-validated near-tie detect (top-2/3 prob gap < TAU) with worklist
// compaction. 128 blocks x 128 threads, one thread per token.
// =====================================================================
__global__ void reduce_detect(const float* __restrict__ part,
                              float* __restrict__ logits,
                              int* __restrict__ nFlag,
                              int* __restrict__ list) {
  const int t = blockIdx.x * 128 + threadIdx.x;
  float l[NE];
#pragma unroll
  for (int i = 0; i < 16; ++i) {
    float4 s = *(const float4*)(part + (size_t)t * NE + 4 * i);
#pragma unroll
    for (int k = 1; k < KSP; ++k) {
      const float4 v = *(const float4*)(part + ((size_t)k * TT + t) * NE + 4 * i);
      s.x += v.x; s.y += v.y; s.z += v.z; s.w += v.w;
    }
    *(float4*)(logits + (size_t)t * NE + 4 * i) = s;
    l[4 * i] = s.x; l[4 * i + 1] = s.y; l[4 * i + 2] = s.z; l[4 * i + 3] = s.w;
  }
  float m = -1e30f;
#pragma unroll
  for (int i = 0; i < NE; ++i) m = fmaxf(m, l[i]);
  float zs = 0.0f;
#pragma unroll
  for (int i = 0; i < NE; ++i) { l[i] = expf(l[i] - m); zs += l[i]; }
  float v1 = -1.0f, v2 = -1.0f, v3 = -1.0f;
#pragma unroll
  for (int i = 0; i < NE; ++i) {
    const float p = l[i];
    if (p > v1)      { v3 = v2; v2 = v1; v1 = p; }
    else if (p > v2) { v3 = v2; v2 = p; }
    else if (p > v3) { v3 = p; }
  }
  const float thr = TAU * zs;
  if (((v1 - v2) < thr) || ((v2 - v3) < thr)) {
    const int k = atomicAdd(nFlag, 1);
    list[k] = t;
  }
}

// =====================================================================
// Kernel 3: fixup — strided worklist, ~1 token/block. Per-token exact
// fp32 recompute (R7-validated semantics), overwriting logits.
// =====================================================================
__global__ void fixup(const float* __restrict__ X,
                      const float* __restrict__ W,
                      const int* __restrict__ nFlag,
                      const int* __restrict__ list,
                      float* __restrict__ logits) {
  __shared__ float red[NE][4];
  const int tid = threadIdx.x;
  const int e   = tid >> 2;
  const int q   = tid & 3;
  const int n   = *nFlag;

  for (int idx = blockIdx.x; idx < n; idx += gridDim.x) {
    const int t = list[idx];
    const float* xr = X + (size_t)t * HD + q * 1024;
    const float* wr = W + (size_t)e * HD + q * 1024;
    float s = 0.0f;
    for (int h = 0; h < 1024; h += 4) {
      const float4 xv = *(const float4*)(xr + h);
      const float4 wv = *(const float4*)(wr + h);
      FMA4(s, xv, wv)
    }
    red[e][q] = s;
    __syncthreads();
    if (q == 0)
      logits[(size_t)t * NE + e] = (red[e][0] + red[e][1]) + (red[e][2] + red[e][3]);
    __syncthreads();
  }
}

// =====================================================================
// Kernel 4: epilogue — validated R1 softmax/top-2/renorm/loss partials,
// reading corrected logits.
// =====================================================================
__global__ void router_epilogue(const float* __restrict__ logits,
                                float* __restrict__ out,
                                float* __restrict__ pP,
                                float* __restrict__ pC,
                                float* __restrict__ pZ) {
  __shared__ float psW[4][NE];
  __shared__ float cf[NE];
  __shared__ float zb[4];

  const int tid  = threadIdx.x;
  const int blk  = blockIdx.x;
  const int tx   = tid & 15;   // expert group (4 experts each)
  const int ty   = tid >> 4;   // token group (2 tokens each)
  const int wv   = tid >> 6;
  const int lane = tid & 63;

  if (tid < NE) cf[tid] = 0.0f;
  __syncthreads();

  float psum[4] = {0.f, 0.f, 0.f, 0.f};
  float zc = 0.0f;
#pragma unroll
  for (int i = 0; i < 2; ++i) {
    const int t = blk * TM + 2 * ty + i;
    const float4 lv = *(const float4*)(logits + (size_t)t * NE + 4 * tx);
    const float l0 = lv.x, l1 = lv.y, l2 = lv.z, l3 = lv.w;

    float m = fmaxf(fmaxf(l0, l1), fmaxf(l2, l3));
    m = fmaxf(m, __shfl_xor(m, 1));
    m = fmaxf(m, __shfl_xor(m, 2));
    m = fmaxf(m, __shfl_xor(m, 4));
    m = fmaxf(m, __shfl_xor(m, 8));
    const float e0 = expf(l0 - m), e1 = expf(l1 - m);
    const float e2 = expf(l2 - m), e3 = expf(l3 - m);
    float zs = (e0 + e1) + (e2 + e3);
    zs += __shfl_xor(zs, 1);
    zs += __shfl_xor(zs, 2);
    zs += __shfl_xor(zs, 4);
    zs += __shfl_xor(zs, 8);
    const float p0 = e0 / zs, p1 = e1 / zs, p2 = e2 / zs, p3 = e3 / zs;
    psum[0] += p0; psum[1] += p1; psum[2] += p2; psum[3] += p3;

    // local top-2 (ascending index => ties keep lower)
    float v1 = p0, v2 = p1; int i1 = 4 * tx, i2 = 4 * tx + 1;
    if (p1 > p0) { v1 = p1; i1 = 4 * tx + 1; v2 = p0; i2 = 4 * tx; }
    if (p2 > v1) { v2 = v1; i2 = i1; v1 = p2; i1 = 4 * tx + 2; }
    else if (p2 > v2) { v2 = p2; i2 = 4 * tx + 2; }
    if (p3 > v1) { v2 = v1; i2 = i1; v1 = p3; i1 = 4 * tx + 3; }
    else if (p3 > v2) { v2 = p3; i2 = 4 * tx + 3; }

    // butterfly merge across the 16 lanes of this token
#pragma unroll
    for (int s = 1; s <= 8; s <<= 1) {
      const float ov1 = __shfl_xor(v1, s); const int oi1 = __shfl_xor(i1, s);
      const float ov2 = __shfl_xor(v2, s); const int oi2 = __shfl_xor(i2, s);
      const bool o1 = (ov1 > v1) || (ov1 == v1 && oi1 < i1);
      if (o1) {
        const bool o2 = (ov2 > v1) || (ov2 == v1 && oi2 < i1);
        v2 = o2 ? ov2 : v1; i2 = o2 ? oi2 : i1;
        v1 = ov1; i1 = oi1;
      } else {
        const bool o2 = (ov1 > v2) || (ov1 == v2 && oi1 < i2);
        v2 = o2 ? ov1 : v2; i2 = o2 ? oi1 : i2;
      }
    }

    const float lz = m + logf(zs);
    if (tx == 0) {
      const float den = v1 + v2 + 1e-9f;
      out[2 * t]     = v1 / den;
      out[2 * t + 1] = v2 / den;
      out[2 * TT + 2 * t]     = (float)i1;
      out[2 * TT + 2 * t + 1] = (float)i2;
      atomicAdd(&cf[i1], 1.0f);
      atomicAdd(&cf[i2], 1.0f);
      zc += lz * lz;
    }
  }

#pragma unroll
  for (int j = 0; j < 4; ++j) {
    psum[j] += __shfl_xor(psum[j], 16);
    psum[j] += __shfl_xor(psum[j], 32);
  }
  if (lane < 16) {
#pragma unroll
    for (int j = 0; j < 4; ++j) psW[wv][4 * lane + j] = psum[j];
  }
  float z = zc;
#pragma unroll
  for (int s = 1; s <= 32; s <<= 1) z += __shfl_xor(z, s);
  if (lane == 0) zb[wv] = z;
  __syncthreads();

  if (tid < NE) {
    pP[blk * NE + tid] = psW[0][tid] + psW[1][tid] + psW[2][tid] + psW[3][tid];
    pC[blk * NE + tid] = cf[tid];
  }
  if (tid == 0) pZ[blk] = zb[0] + zb[1] + zb[2] + zb[3];
}

__global__ void router_final(const float* __restrict__ pP,
                             const float* __restrict__ pC,
                             const float* __restrict__ pZ,
                             float* __restrict__ out) {
  const int e = threadIdx.x;  // 64 threads = 1 wave
  float sP = 0.f, sC = 0.f;
  for (int b = 0; b < NBLK; ++b) {
    sP += pP[b * NE + e];
    sC += pC[b * NE + e];
  }
  const float f = sC * (1.0f / (TT * 2.0f));
  const float P = sP * (1.0f / (float)TT);
  out[4 * TT + 2 + e] = f;
  float term = f * P;
#pragma unroll
  for (int s = 1; s <= 32; s <<= 1) term += __shfl_xor(term, s);
  float zs = 0.f;
  for (int b = e; b < NBLK; b += NE) zs += pZ[b];
#pragma unroll
  for (int s = 1; s <= 32; s <<= 1) zs += __shfl_xor(zs, s);
  if (e == 0) {
    out[4 * TT]     = 0.01f * ((float)NE * term);
    out[4 * TT + 1] = 0.001f * (zs / (float)TT);
  }
}

// =====================================================================
// Fallback (validated round-1 fused kernel) for tiny ws_size.
// =====================================================================
__device__ __forceinline__ void async_copy16f(const float* src, float* dst) {
  async16((const void*)src, (void*)dst);
}

__launch_bounds__(256, 2)
__global__ void router_fused(const float* __restrict__ X,
                             const float* __restrict__ W,
                             float* __restrict__ out,
                             float* __restrict__ pP,
                             float* __restrict__ pC,
                             float* __restrict__ pZ) {
  __shared__ __align__(16) float sH[2][TM * 64];
  __shared__ __align__(16) float sW[2][NE * 64];
  __shared__ float psW[4][NE];
  __shared__ float cf[NE];
  __shared__ float zb[4];

  const int tid  = threadIdx.x;
  const int blk  = blockIdx.x;
  const int tx   = tid & 15;
  const int ty   = tid >> 4;
  const int wv   = tid >> 6;
  const int lane = tid & 63;

  if (tid < NE) cf[tid] = 0.0f;

  const int xoff = (tid & 15) << 4;
  const float* srcH[2];
  const float* srcW[4];
#pragma unroll
  for (int p = 0; p < 2; ++p) {
    const int r = ty + p * 16;
    const int sw = ((r >> 1) & 7) << 4;
    srcH[p] = X + (size_t)(blk * TM + r) * HD + ((xoff ^ sw) >> 2);
  }
#pragma unroll
  for (int p = 0; p < 4; ++p) {
    const int e = ty + p * 16;
    const int sw = ((e >> 2) & 7) << 4;
    srcW[p] = W + (size_t)e * HD + ((xoff ^ sw) >> 2);
  }

  auto stage = [&](int b, int kt) {
    const int o = kt * 64;
    float* dH = &sH[b][wv * 256];
    async_copy16f(srcH[0] + o, dH);
    async_copy16f(srcH[1] + o, dH + 1024);
    float* dW = &sW[b][wv * 256];
    async_copy16f(srcW[0] + o, dW);
    async_copy16f(srcW[1] + o, dW + 1024);
    async_copy16f(srcW[2] + o, dW + 2048);
    async_copy16f(srcW[3] + o, dW + 3072);
  };

  float acc[2][4] = {{0.f, 0.f, 0.f, 0.f}, {0.f, 0.f, 0.f, 0.f}};
  const int Hswz = (ty & 7) << 4;
  const int Wswz = (tx & 7) << 4;

  auto compute = [&](int b) {
    const char* hb = (const char*)(&sH[b][0]) + (ty << 9);
    const char* wb = (const char*)(&sW[b][0]) + (tx << 10);
#pragma unroll
    for (int h4 = 0; h4 < 16; ++h4) {
      const int oH = (h4 << 4) ^ Hswz;
      const int oW = (h4 << 4) ^ Wswz;
      const float4 h0 = *(const float4*)(hb + oH);
      const float4 h1 = *(const float4*)(hb + oH + 256);
      const float4 w0 = *(const float4*)(wb + oW);
      const float4 w1 = *(const float4*)(wb + oW + 256);
      const float4 w2 = *(const float4*)(wb + oW + 512);
      const float4 w3 = *(const float4*)(wb + oW + 768);
      FMA4(acc[0][0], h0, w0) FMA4(acc[0][1], h0, w1)
      FMA4(acc[0][2], h0, w2) FMA4(acc[0][3], h0, w3)
      FMA4(acc[1][0], h1, w0) FMA4(acc[1][1], h1, w1)
      FMA4(acc[1][2], h1, w2) FMA4(acc[1][3], h1, w3)
    }
  };

  int buf = 0;
  stage(0, 0);
  __syncthreads();
  for (int kt = 0; kt < 64; ++kt) {
    if (kt + 1 < 64) stage(buf ^ 1, kt + 1);
    compute(buf);
    __syncthreads();
    buf ^= 1;
  }

  float psum[4] = {0.f, 0.f, 0.f, 0.f};
  float zc = 0.0f;
#pragma unroll
  for (int i = 0; i < 2; ++i) {
    const float l0 = acc[i][0], l1 = acc[i][1], l2 = acc[i][2], l3 = acc[i][3];
    float m = fmaxf(fmaxf(l0, l1), fmaxf(l2, l3));
    m = fmaxf(m, __shfl_xor(m, 1));
    m = fmaxf(m, __shfl_xor(m, 2));
    m = fmaxf(m, __shfl_xor(m, 4));
    m = fmaxf(m, __shfl_xor(m, 8));
    const float e0 = expf(l0 - m), e1 = expf(l1 - m);
    const float e2 = expf(l2 - m), e3 = expf(l3 - m);
    float zs = (e0 + e1) + (e2 + e3);
    zs += __shfl_xor(zs, 1);
    zs += __shfl_xor(zs, 2);
    zs += __shfl_xor(zs, 4);
    zs += __shfl_xor(zs, 8);
    const float p0 = e0 / zs, p1 = e1 / zs, p2 = e2 / zs, p3 = e3 / zs;
    psum[0] += p0; psum[1] += p1; psum[2] += p2; psum[3] += p3;

    float v1 = p0, v2 = p1; int i1 = 4 * tx, i2 = 4 * tx + 1;
    if (p1 > p0) { v1 = p1; i1 = 4 * tx + 1; v2 = p0; i2 = 4 * tx; }
    if (p2 > v1) { v2 = v1; i2 = i1; v1 = p2; i1 = 4 * tx + 2; }
    else if (p2 > v2) { v2 = p2; i2 = 4 * tx + 2; }
    if (p3 > v1) { v2 = v1; i2 = i1; v1 = p3; i1 = 4 * tx + 3; }
    else if (p3 > v2) { v2 = p3; i2 = 4 * tx + 3; }

#pragma unroll
    for (int s = 1; s <= 8; s <<= 1) {
      const float ov1 = __shfl_xor(v1, s); const int oi1 = __shfl_xor(i1, s);
      const float ov2 = __shfl_xor(v2, s); const int oi2 = __shfl_xor(i2, s);
      const bool o1 = (ov1 > v1) || (ov1 == v1 && oi1 < i1);
      if (o1) {
        const bool o2 = (ov2 > v1) || (ov2 == v1 && oi2 < i1);
        v2 = o2 ? ov2 : v1; i2 = o2 ? oi2 : i1;
        v1 = ov1; i1 = oi1;
      } else {
        const bool o2 = (ov1 > v2) || (ov1 == v2 && oi1 < i2);
        v2 = o2 ? ov1 : v2; i2 = o2 ? oi1 : i2;
      }
    }

    const float lz = m + logf(zs);
    if (tx == 0) {
      const int t = blk * TM + 2 * ty + i;
      const float den = v1 + v2 + 1e-9f;
      out[2 * t]     = v1 / den;
      out[2 * t + 1] = v2 / den;
      out[2 * TT + 2 * t]     = (float)i1;
      out[2 * TT + 2 * t + 1] = (float)i2;
      atomicAdd(&cf[i1], 1.0f);
      atomicAdd(&cf[i2], 1.0f);
      zc += lz * lz;
    }
  }

#pragma unroll
  for (int j = 0; j < 4; ++j) {
    psum[j] += __shfl_xor(psum[j], 16);
    psum[j] += __shfl_xor(psum[j], 32);
  }
  if (lane < 16) {
#pragma unroll
    for (int j = 0; j < 4; ++j) psW[wv][4 * lane + j] = psum[j];
  }
  float z = zc;
#pragma unroll
  for (int s = 1; s <= 32; s <<= 1) z += __shfl_xor(z, s);
  if (lane == 0) zb[wv] = z;
  __syncthreads();

  if (tid < NE) {
    pP[blk * NE + tid] = psW[0][tid] + psW[1][tid] + psW[2][tid] + psW[3][tid];
    pC[blk * NE + tid] = cf[tid];
  }
  if (tid == 0) pZ[blk] = zb[0] + zb[1] + zb[2] + zb[3];
}

extern "C" void kernel_launch(void* const* d_in, const int* in_sizes, int n_in,
                              void* d_out, int out_size, void* d_ws, size_t ws_size,
                              hipStream_t stream) {
  const float* X = (const float*)d_in[0];   // [16384, 4096] f32
  const float* W = (const float*)d_in[1];   // [64, 4096] f32
  float* out = (float*)d_out;
  (void)in_sizes; (void)n_in; (void)out_size;

  // ws: WH, WL (ushort 64*4096 each), part f32[4][TT][NE], logits f32[TT][NE],
  //     pP, pC, pZ, nFlag, list
  const size_t WHALF = (size_t)NE * HD;                 // ushorts per plane
  const size_t PART6 = (size_t)KSP * TT * NE;           // floats
  const size_t LOGF  = (size_t)TT * NE;                 // floats
  const size_t AUXF  = (size_t)NBLK * NE * 2 + NBLK;
  const size_t NEEDB = WHALF * 2 * sizeof(unsigned short) +
                       (PART6 + LOGF + AUXF) * sizeof(float) +
                       (1 + TT) * sizeof(int);

  if (ws_size >= NEEDB) {
    unsigned short* WH = (unsigned short*)d_ws;
    unsigned short* WL = WH + WHALF;
    float* part   = (float*)(WL + WHALF);
    float* logits = part + PART6;
    float* pP = logits + LOGF;
    float* pC = pP + NBLK * NE;
    float* pZ = pC + NBLK * NE;
    int* nFlag = (int*)(pZ + NBLK);
    int* list  = nFlag + 1;
    hipMemsetAsync(nFlag, 0, sizeof(int), stream);
    wconv<<<dim3(256), dim3(256), 0, stream>>>(W, WH, WL);
    gemm_v6<<<dim3(NTB6 * KSP), dim3(256), 0, stream>>>(X, WH, WL, part);
    reduce_detect<<<dim3(TT / 128), dim3(128), 0, stream>>>(part, logits, nFlag, list);
    fixup<<<dim3(512), dim3(256), 0, stream>>>(X, W, nFlag, list, logits);
    router_epilogue<<<dim3(NBLK), dim3(256), 0, stream>>>(logits, out, pP, pC, pZ);
    router_final<<<dim3(1), dim3(NE), 0, stream>>>(pP, pC, pZ, out);
  } else {
    float* pP = (float*)d_ws;
    float* pC = pP + NBLK * NE;
    float* pZ = pC + NBLK * NE;
    router_fused<<<dim3(NBLK), dim3(256), 0, stream>>>(X, W, out, pP, pC, pZ);
    router_final<<<dim3(1), dim3(NE), 0, stream>>>(pP, pC, pZ, out);
  }
}